// Round 9
// baseline (329.066 us; speedup 1.0000x reference)
//
#include <hip/hip_runtime.h>
#include <cfloat>
#include <cmath>

#define CCH 256   // channels
#define HID 16    // hidden = C / R

typedef float f32x4 __attribute__((ext_vector_type(4)));

// Round-2 fused structure at DOUBLE the TLP: 512 blocks x 1024 threads
// (16 waves), 2 blocks/CU -> 32 waves/CU. Plain __launch_bounds__(1024):
// R8 proved this body compiles to 64 VGPR with no scratch spills (R5's
// regression was the (1024,8) clamp forcing VGPR=32 -> 98 MB spill traffic).
//   1. stream segment (float4, 2 rows in flight/wave), sum+max per channel
//   2. LDS reduce (16 wave-groups) -> avg/max pools
//   3. fused MLP: att = sigmoid((relu(avg@W1+b1)+relu(max@W1+b1))@W2 + 2*b2)
//   4. apply att to own segment in REVERSE order (re-read hits L3; FETCH
//      has shown exactly one x read in every fused round). NT stores.
__global__ __launch_bounds__(1024) void fused_gca_kernel(
    const float* __restrict__ x, const int* __restrict__ seg,
    const int* __restrict__ numg,
    const float* __restrict__ W1, const float* __restrict__ b1,
    const float* __restrict__ W2, const float* __restrict__ b2,
    float* __restrict__ out, int N)
{
    const int G = *numg;
    const int tid = (int)threadIdx.x;
    const int c4  = tid & 63;   // lane: which float4 of the 256-ch row
    const int r   = tid >> 6;   // wave id 0..15 = row group

    __shared__ f32x4 lsum[1024];
    __shared__ f32x4 lmax[1024];
    __shared__ float pool2[2 * CCH];   // [0:256) avg, [256:512) max
    __shared__ float ht[2 * HID];
    __shared__ float attn[CCH];

    for (int g = (int)blockIdx.x; g < G; g += (int)gridDim.x) {
        // ---- segment bounds: lower_bound(g), lower_bound(g+1) ----
        int lo = 0, hi = N;
        while (lo < hi) { int mid = (lo + hi) >> 1; if (seg[mid] < g) lo = mid + 1; else hi = mid; }
        const int start = lo;
        hi = N;
        while (lo < hi) { int mid = (lo + hi) >> 1; if (seg[mid] <= g) lo = mid + 1; else hi = mid; }
        const int end = lo;
        const int count = end - start;

        // ---- phase 1: pooling stream, rows start+r step 16, 2-deep ----
        f32x4 s = {0.f, 0.f, 0.f, 0.f};
        f32x4 m = {-FLT_MAX, -FLT_MAX, -FLT_MAX, -FLT_MAX};
        const float* xp = x + (size_t)c4 * 4;
        int n = start + r;
        for (; n + 16 < end; n += 32) {
            const f32x4 v0 = *reinterpret_cast<const f32x4*>(xp + (size_t)(n)      * CCH);
            const f32x4 v1 = *reinterpret_cast<const f32x4*>(xp + (size_t)(n + 16) * CCH);
            s += v0;
            m.x = fmaxf(m.x, v0.x); m.y = fmaxf(m.y, v0.y);
            m.z = fmaxf(m.z, v0.z); m.w = fmaxf(m.w, v0.w);
            s += v1;
            m.x = fmaxf(m.x, v1.x); m.y = fmaxf(m.y, v1.y);
            m.z = fmaxf(m.z, v1.z); m.w = fmaxf(m.w, v1.w);
        }
        if (n < end) {
            const f32x4 v0 = *reinterpret_cast<const f32x4*>(xp + (size_t)n * CCH);
            s += v0;
            m.x = fmaxf(m.x, v0.x); m.y = fmaxf(m.y, v0.y);
            m.z = fmaxf(m.z, v0.z); m.w = fmaxf(m.w, v0.w);
        }
        lsum[tid] = s; lmax[tid] = m;
        __syncthreads();

        // ---- phase 2: cross-wave reduce (64 threads own 4 channels each) ----
        if (tid < 64) {
            f32x4 S = lsum[tid];
            f32x4 M = lmax[tid];
            #pragma unroll
            for (int k = 1; k < 16; ++k) {
                const f32x4 S2 = lsum[tid + 64 * k];
                const f32x4 M2 = lmax[tid + 64 * k];
                S += S2;
                M.x = fmaxf(M.x, M2.x); M.y = fmaxf(M.y, M2.y);
                M.z = fmaxf(M.z, M2.z); M.w = fmaxf(M.w, M2.w);
            }
            const float inv = (count > 0) ? 1.0f / (float)count : 0.0f;
            pool2[4 * tid + 0] = S.x * inv;
            pool2[4 * tid + 1] = S.y * inv;
            pool2[4 * tid + 2] = S.z * inv;
            pool2[4 * tid + 3] = S.w * inv;
            pool2[CCH + 4 * tid + 0] = (count > 0) ? M.x : 0.0f;
            pool2[CCH + 4 * tid + 1] = (count > 0) ? M.y : 0.0f;
            pool2[CCH + 4 * tid + 2] = (count > 0) ? M.z : 0.0f;
            pool2[CCH + 4 * tid + 3] = (count > 0) ? M.w : 0.0f;
        }
        __syncthreads();

        // ---- phase 3a: hidden layer (512 threads, 16 per (pool,j) pair) ----
        if (tid < 512) {
            const int pair = tid >> 4;        // 0..31: pool = pair>>4, j = pair&15
            const int sub  = tid & 15;
            const int j    = pair & (HID - 1);
            const float* p = pool2 + (pair >> 4) * CCH;
            float h = 0.f;
            #pragma unroll
            for (int c = sub; c < CCH; c += 16)
                h = fmaf(p[c], W1[c * HID + j], h);
            h += __shfl_xor(h, 8, 64);
            h += __shfl_xor(h, 4, 64);
            h += __shfl_xor(h, 2, 64);
            h += __shfl_xor(h, 1, 64);
            if (sub == 0) ht[pair] = fmaxf(h + b1[j], 0.0f);
        }
        __syncthreads();

        // ---- phase 3b: output layer + sigmoid ----
        if (tid < CCH) {
            float acc = 2.0f * b2[tid];
            #pragma unroll
            for (int j = 0; j < HID; ++j)
                acc = fmaf(ht[j] + ht[HID + j], W2[j * CCH + tid], acc);
            attn[tid] = 1.0f / (1.0f + expf(-acc));
        }
        __syncthreads();

        // ---- phase 4: apply, reverse order for L3 reuse, NT stores ----
        {
            const f32x4 a4 = *reinterpret_cast<const f32x4*>(attn + c4 * 4);
            const int rem = end - (start + r);
            if (rem > 0) {
                int k = ((rem + 15) >> 4) - 1;   // last row index (stride 16)
                const float* xq = x   + (size_t)(start + r) * CCH + (size_t)c4 * 4;
                float*       oq = out + (size_t)(start + r) * CCH + (size_t)c4 * 4;
                for (; k >= 1; k -= 2) {
                    const size_t i0 = (size_t)(k)     * (16 * CCH);
                    const size_t i1 = (size_t)(k - 1) * (16 * CCH);
                    const f32x4 v0 = *reinterpret_cast<const f32x4*>(xq + i0);
                    const f32x4 v1 = *reinterpret_cast<const f32x4*>(xq + i1);
                    __builtin_nontemporal_store(v0 * a4, reinterpret_cast<f32x4*>(oq + i0));
                    __builtin_nontemporal_store(v1 * a4, reinterpret_cast<f32x4*>(oq + i1));
                }
                if (k == 0) {
                    const f32x4 v0 = *reinterpret_cast<const f32x4*>(xq);
                    __builtin_nontemporal_store(v0 * a4, reinterpret_cast<f32x4*>(oq));
                }
            }
        }
        __syncthreads();  // protect LDS reuse on next grid-stride iteration
    }
}

extern "C" void kernel_launch(void* const* d_in, const int* in_sizes, int n_in,
                              void* d_out, int out_size, void* d_ws, size_t ws_size,
                              hipStream_t stream) {
    const float* x    = (const float*)d_in[0];
    const int*   seg  = (const int*)d_in[1];   // sorted segment ids (int32)
    const int*   numg = (const int*)d_in[2];   // num_graphs scalar (device read)
    const float* W1   = (const float*)d_in[3]; // [C, H]
    const float* b1   = (const float*)d_in[4]; // [H]
    const float* W2   = (const float*)d_in[5]; // [H, C]
    const float* b2   = (const float*)d_in[6]; // [C]
    float* out = (float*)d_out;

    const int N = in_sizes[1];                 // number of nodes

    fused_gca_kernel<<<512, 1024, 0, stream>>>(x, seg, numg, W1, b1, W2, b2, out, N);
}

// Round 10
// 293.142 us; speedup vs baseline: 1.1226x; 1.1226x over previous
//
#include <hip/hip_runtime.h>
#include <cfloat>
#include <cmath>

#define CCH 256   // channels
#define HID 16    // hidden = C / R

typedef float f32x4 __attribute__((ext_vector_type(4)));

// Round-2 fused kernel (285 us best: 512x512, NT reverse apply) with ONE
// change: pool loop issues 8 row-loads in flight (64 KB instantaneous dense
// window per block, up from 16 KB) to test the DRAM-page-span theory --
// a page's addresses span ~64-128 KB of contiguous space; a block must
// cover that span quickly or pages get reopened 4-8x (the ~40% BW loss
// every per-graph variant has shown vs the linear-shape 6.3-6.7 TB/s).
__global__ __launch_bounds__(512) void fused_gca_kernel(
    const float* __restrict__ x, const int* __restrict__ seg,
    const int* __restrict__ numg,
    const float* __restrict__ W1, const float* __restrict__ b1,
    const float* __restrict__ W2, const float* __restrict__ b2,
    float* __restrict__ out, int N)
{
    const int G = *numg;
    const int tid = (int)threadIdx.x;
    const int c4  = tid & 63;   // lane: which float4 of the 256-ch row
    const int r   = tid >> 6;   // wave id 0..7 = row group

    __shared__ f32x4 lsum[512];
    __shared__ f32x4 lmax[512];
    __shared__ float pool2[2 * CCH];   // [0:256) avg, [256:512) max
    __shared__ float ht[2 * HID];
    __shared__ float attn[CCH];

    for (int g = (int)blockIdx.x; g < G; g += (int)gridDim.x) {
        // ---- segment bounds: lower_bound(g), lower_bound(g+1) ----
        int lo = 0, hi = N;
        while (lo < hi) { int mid = (lo + hi) >> 1; if (seg[mid] < g) lo = mid + 1; else hi = mid; }
        const int start = lo;
        hi = N;
        while (lo < hi) { int mid = (lo + hi) >> 1; if (seg[mid] <= g) lo = mid + 1; else hi = mid; }
        const int end = lo;
        const int count = end - start;

        // ---- phase 1: pooling stream, 8 rows (8 KB/wave) in flight ----
        // Block instant window: 8 waves x 8 rows = 64 rows = 64 KB dense.
        f32x4 s = {0.f, 0.f, 0.f, 0.f};
        f32x4 m = {-FLT_MAX, -FLT_MAX, -FLT_MAX, -FLT_MAX};
        const float* xp = x + (size_t)c4 * 4;
        int n = start + r;
        for (; n + 56 < end; n += 64) {
            f32x4 v0 = *reinterpret_cast<const f32x4*>(xp + (size_t)(n)      * CCH);
            f32x4 v1 = *reinterpret_cast<const f32x4*>(xp + (size_t)(n +  8) * CCH);
            f32x4 v2 = *reinterpret_cast<const f32x4*>(xp + (size_t)(n + 16) * CCH);
            f32x4 v3 = *reinterpret_cast<const f32x4*>(xp + (size_t)(n + 24) * CCH);
            f32x4 v4 = *reinterpret_cast<const f32x4*>(xp + (size_t)(n + 32) * CCH);
            f32x4 v5 = *reinterpret_cast<const f32x4*>(xp + (size_t)(n + 40) * CCH);
            f32x4 v6 = *reinterpret_cast<const f32x4*>(xp + (size_t)(n + 48) * CCH);
            f32x4 v7 = *reinterpret_cast<const f32x4*>(xp + (size_t)(n + 56) * CCH);
            s += v0;
            m.x = fmaxf(m.x, v0.x); m.y = fmaxf(m.y, v0.y);
            m.z = fmaxf(m.z, v0.z); m.w = fmaxf(m.w, v0.w);
            s += v1;
            m.x = fmaxf(m.x, v1.x); m.y = fmaxf(m.y, v1.y);
            m.z = fmaxf(m.z, v1.z); m.w = fmaxf(m.w, v1.w);
            s += v2;
            m.x = fmaxf(m.x, v2.x); m.y = fmaxf(m.y, v2.y);
            m.z = fmaxf(m.z, v2.z); m.w = fmaxf(m.w, v2.w);
            s += v3;
            m.x = fmaxf(m.x, v3.x); m.y = fmaxf(m.y, v3.y);
            m.z = fmaxf(m.z, v3.z); m.w = fmaxf(m.w, v3.w);
            s += v4;
            m.x = fmaxf(m.x, v4.x); m.y = fmaxf(m.y, v4.y);
            m.z = fmaxf(m.z, v4.z); m.w = fmaxf(m.w, v4.w);
            s += v5;
            m.x = fmaxf(m.x, v5.x); m.y = fmaxf(m.y, v5.y);
            m.z = fmaxf(m.z, v5.z); m.w = fmaxf(m.w, v5.w);
            s += v6;
            m.x = fmaxf(m.x, v6.x); m.y = fmaxf(m.y, v6.y);
            m.z = fmaxf(m.z, v6.z); m.w = fmaxf(m.w, v6.w);
            s += v7;
            m.x = fmaxf(m.x, v7.x); m.y = fmaxf(m.y, v7.y);
            m.z = fmaxf(m.z, v7.z); m.w = fmaxf(m.w, v7.w);
        }
        for (; n < end; n += 8) {
            const f32x4 v0 = *reinterpret_cast<const f32x4*>(xp + (size_t)n * CCH);
            s += v0;
            m.x = fmaxf(m.x, v0.x); m.y = fmaxf(m.y, v0.y);
            m.z = fmaxf(m.z, v0.z); m.w = fmaxf(m.w, v0.w);
        }
        lsum[tid] = s; lmax[tid] = m;
        __syncthreads();

        // ---- phase 2: cross-wave reduce (64 threads own 4 channels each) ----
        if (tid < 64) {
            f32x4 S = lsum[tid];
            f32x4 M = lmax[tid];
            #pragma unroll
            for (int k = 1; k < 8; ++k) {
                const f32x4 S2 = lsum[tid + 64 * k];
                const f32x4 M2 = lmax[tid + 64 * k];
                S += S2;
                M.x = fmaxf(M.x, M2.x); M.y = fmaxf(M.y, M2.y);
                M.z = fmaxf(M.z, M2.z); M.w = fmaxf(M.w, M2.w);
            }
            const float inv = (count > 0) ? 1.0f / (float)count : 0.0f;
            pool2[4 * tid + 0] = S.x * inv;
            pool2[4 * tid + 1] = S.y * inv;
            pool2[4 * tid + 2] = S.z * inv;
            pool2[4 * tid + 3] = S.w * inv;
            pool2[CCH + 4 * tid + 0] = (count > 0) ? M.x : 0.0f;
            pool2[CCH + 4 * tid + 1] = (count > 0) ? M.y : 0.0f;
            pool2[CCH + 4 * tid + 2] = (count > 0) ? M.z : 0.0f;
            pool2[CCH + 4 * tid + 3] = (count > 0) ? M.w : 0.0f;
        }
        __syncthreads();

        // ---- phase 3a: hidden layer (16 threads per (pool,j) pair) ----
        {
            const int pair = tid >> 4;        // 0..31: pool = pair>>4, j = pair&15
            const int sub  = tid & 15;
            const int j    = pair & (HID - 1);
            const float* p = pool2 + (pair >> 4) * CCH;
            float h = 0.f;
            #pragma unroll
            for (int c = sub; c < CCH; c += 16)
                h = fmaf(p[c], W1[c * HID + j], h);
            h += __shfl_xor(h, 8, 64);
            h += __shfl_xor(h, 4, 64);
            h += __shfl_xor(h, 2, 64);
            h += __shfl_xor(h, 1, 64);
            if (sub == 0) ht[pair] = fmaxf(h + b1[j], 0.0f);
        }
        __syncthreads();

        // ---- phase 3b: output layer + sigmoid ----
        if (tid < CCH) {
            float acc = 2.0f * b2[tid];
            #pragma unroll
            for (int j = 0; j < HID; ++j)
                acc = fmaf(ht[j] + ht[HID + j], W2[j * CCH + tid], acc);
            attn[tid] = 1.0f / (1.0f + expf(-acc));
        }
        __syncthreads();

        // ---- phase 4: apply, reverse order for L3 reuse, NT stores ----
        {
            const f32x4 a4 = *reinterpret_cast<const f32x4*>(attn + c4 * 4);
            const int rem = end - (start + r);
            if (rem > 0) {
                int k = ((rem + 7) >> 3) - 1;   // last row index for this wave
                const float* xq = x   + (size_t)(start + r) * CCH + (size_t)c4 * 4;
                float*       oq = out + (size_t)(start + r) * CCH + (size_t)c4 * 4;
                for (; k >= 1; k -= 2) {
                    const size_t i0 = (size_t)(k)     * (8 * CCH);
                    const size_t i1 = (size_t)(k - 1) * (8 * CCH);
                    const f32x4 v0 = *reinterpret_cast<const f32x4*>(xq + i0);
                    const f32x4 v1 = *reinterpret_cast<const f32x4*>(xq + i1);
                    __builtin_nontemporal_store(v0 * a4, reinterpret_cast<f32x4*>(oq + i0));
                    __builtin_nontemporal_store(v1 * a4, reinterpret_cast<f32x4*>(oq + i1));
                }
                if (k == 0) {
                    const f32x4 v0 = *reinterpret_cast<const f32x4*>(xq);
                    __builtin_nontemporal_store(v0 * a4, reinterpret_cast<f32x4*>(oq));
                }
            }
        }
        __syncthreads();  // protect LDS reuse on next grid-stride iteration
    }
}

extern "C" void kernel_launch(void* const* d_in, const int* in_sizes, int n_in,
                              void* d_out, int out_size, void* d_ws, size_t ws_size,
                              hipStream_t stream) {
    const float* x    = (const float*)d_in[0];
    const int*   seg  = (const int*)d_in[1];   // sorted segment ids (int32)
    const int*   numg = (const int*)d_in[2];   // num_graphs scalar (device read)
    const float* W1   = (const float*)d_in[3]; // [C, H]
    const float* b1   = (const float*)d_in[4]; // [H]
    const float* W2   = (const float*)d_in[5]; // [H, C]
    const float* b2   = (const float*)d_in[6]; // [C]
    float* out = (float*)d_out;

    const int N = in_sizes[1];                 // number of nodes

    fused_gca_kernel<<<512, 512, 0, stream>>>(x, seg, numg, W1, b1, W2, b2, out, N);
}